// Round 1
// baseline (506.522 us; speedup 1.0000x reference)
//
#include <hip/hip_runtime.h>
#include <hip/hip_bf16.h>

// HeteAggregator: B=20000, N=32, D=128 (fp32 in/out, bf16 MFMA inside)
//
// per b:  msg[n][e] = sum_d nb[b][n][d] * w[d][e]          (MFMA, bf16)
//         score[n]  = sum_d leaky(self[b][d]*msg[n][d]) * q[d]
//         alpha     = softmax_n(score)
//         out[b][e] = sum_n alpha[n] * msg[n][e]

#define NNBR 32
#define DIM  128
#define BPB  8      // b's per block -> 2500 blocks

typedef short  short8 __attribute__((ext_vector_type(8)));
typedef float  f32x4  __attribute__((ext_vector_type(4)));

__device__ __forceinline__ ushort f2bf(float x) {
    // fp32 -> bf16 round-to-nearest-even
    uint u = __float_as_uint(x);
    u += 0x7FFFu + ((u >> 16) & 1u);
    return (ushort)(u >> 16);
}

__global__ __launch_bounds__(256) void hete_agg_kernel(
    const float* __restrict__ selfv,  // [B,128]
    const float* __restrict__ nbr,    // [B,32,128]
    const float* __restrict__ w,      // [128,128]
    const float* __restrict__ q,      // [128,1]
    float* __restrict__ out)          // [B,128]
{
    __shared__ ushort nbs[NNBR * DIM];          // bf16 neighbor tile, XOR-swizzled rows (256B/row)
    __shared__ float  msg[NNBR * (DIM + 1)];    // fp32 messages, +1 pad vs bank conflicts
    __shared__ float  sfl[DIM];
    __shared__ float  qs[DIM];
    __shared__ float  scoreL[NNBR];
    __shared__ float  alphaL[NNBR];

    const int tid = threadIdx.x;
    const int l   = tid & 63;
    const int wid = tid >> 6;
    const int mt  = wid & 1;     // m-tile: n-rows [mt*16, mt*16+16)
    const int ng  = wid >> 1;    // e-group: cols [ng*64, ng*64+64)
    const int lr  = l & 15;      // row (A) / col (B,D) within 16x16 tile
    const int lk  = l >> 4;      // k-group 0..3

    if (tid < 32) {
        float4 v = *(const float4*)(q + tid * 4);
        *(float4*)(qs + tid * 4) = v;
    }

    // ---- preload B-fragments of w (bf16) into registers; reused for all BPB b's ----
    // b_frag element i = w[kk*32 + lk*8 + i][ng*64 + nt*16 + lr]
    short8 bfrag[4][4];   // [nt][kk]
    {
        const int colE = ng * 64 + lr;
        #pragma unroll
        for (int nt = 0; nt < 4; ++nt) {
            #pragma unroll
            for (int kk = 0; kk < 4; ++kk) {
                short8 f;
                #pragma unroll
                for (int i = 0; i < 8; ++i) {
                    int krow = kk * 32 + lk * 8 + i;
                    f[i] = (short)f2bf(w[krow * DIM + colE + nt * 16]);
                }
                bfrag[nt][kk] = f;
            }
        }
    }

    for (int bi = 0; bi < BPB; ++bi) {
        const int b = blockIdx.x * BPB + bi;

        // ---- stage neighbor tile fp32 -> bf16 LDS (swizzled); self -> LDS ----
        {
            const float4* src = (const float4*)(nbr + (size_t)b * NNBR * DIM);
            #pragma unroll
            for (int it = 0; it < 4; ++it) {
                int f   = tid + it * 256;       // float4 index 0..1023
                int row = f >> 5;               // 32 float4 per 128-wide row
                int c4  = (f & 31) * 4;         // ushort col
                float4 v = src[f];
                ushort4 bv;
                bv.x = f2bf(v.x); bv.y = f2bf(v.y);
                bv.z = f2bf(v.z); bv.w = f2bf(v.w);
                int col = c4 ^ ((row & 7) << 3);   // 16B-granule XOR swizzle
                *(ushort4*)(&nbs[row * DIM + col]) = bv;
            }
            if (tid < 32) {
                float4 v = *(const float4*)(selfv + (size_t)b * DIM + tid * 4);
                *(float4*)(sfl + tid * 4) = v;
            }
        }
        __syncthreads();

        // ---- MFMA: msg = nb x w  (M=32 n-rows, N=128 e-cols, K=128 d) ----
        f32x4 acc[4] = {};   // one 16x16 tile per nt
        #pragma unroll
        for (int kk = 0; kk < 4; ++kk) {
            int row = mt * 16 + lr;
            int col = (kk * 32 + lk * 8) ^ ((row & 7) << 3);
            short8 a = *(const short8*)(&nbs[row * DIM + col]);
            #pragma unroll
            for (int nt = 0; nt < 4; ++nt)
                acc[nt] = __builtin_amdgcn_mfma_f32_16x16x32_bf16(a, bfrag[nt][kk], acc[nt], 0, 0, 0);
        }

        // ---- write msg to LDS (C/D layout: col=lane&15, row=(lane>>4)*4+reg) ----
        #pragma unroll
        for (int nt = 0; nt < 4; ++nt) {
            #pragma unroll
            for (int r = 0; r < 4; ++r) {
                int row = mt * 16 + lk * 4 + r;
                int col = ng * 64 + nt * 16 + lr;
                msg[row * (DIM + 1) + col] = acc[nt][r];
            }
        }
        __syncthreads();

        // ---- scores: 8 threads per n, 16 d each ----
        {
            int n  = tid >> 3;
            int d0 = (tid & 7) * 16;
            float p = 0.f;
            #pragma unroll
            for (int j = 0; j < 16; ++j) {
                int d = d0 + j;
                float m = msg[n * (DIM + 1) + d];
                float a = sfl[d] * m;
                a = (a >= 0.f) ? a : 0.2f * a;   // LeakyReLU
                p += a * qs[d];
            }
            #pragma unroll
            for (int off = 1; off < 8; off <<= 1) p += __shfl_xor(p, off);
            if ((tid & 7) == 0) scoreL[n] = p;
        }
        __syncthreads();

        // ---- softmax over 32 neighbors (lanes 0..31 of wave 0) ----
        if (tid < 32) {
            float s = scoreL[tid];
            float m = s;
            #pragma unroll
            for (int off = 1; off < 32; off <<= 1) m = fmaxf(m, __shfl_xor(m, off));
            float e = __expf(s - m);
            float sum = e;
            #pragma unroll
            for (int off = 1; off < 32; off <<= 1) sum += __shfl_xor(sum, off);
            alphaL[tid] = e / sum;
        }
        __syncthreads();

        // ---- weighted sum over neighbors ----
        if (tid < DIM) {
            float o = 0.f;
            #pragma unroll
            for (int n = 0; n < NNBR; ++n)
                o += alphaL[n] * msg[n * (DIM + 1) + tid];
            out[(size_t)b * DIM + tid] = o;
        }
        __syncthreads();   // LDS reused next iteration
    }
}

extern "C" void kernel_launch(void* const* d_in, const int* in_sizes, int n_in,
                              void* d_out, int out_size, void* d_ws, size_t ws_size,
                              hipStream_t stream) {
    const float* selfv = (const float*)d_in[0];
    const float* nbr   = (const float*)d_in[1];
    const float* w     = (const float*)d_in[2];
    const float* q     = (const float*)d_in[3];
    float* out = (float*)d_out;

    const int B = in_sizes[0] / DIM;          // 20000
    const int nblocks = B / BPB;              // 2500
    hete_agg_kernel<<<nblocks, 256, 0, stream>>>(selfv, nbr, w, q, out);
}

// Round 3
// 504.021 us; speedup vs baseline: 1.0050x; 1.0050x over previous
//
#include <hip/hip_runtime.h>
#include <hip/hip_bf16.h>

// HeteAggregator: B=20000, N=32, D=128 (fp32 in/out, bf16 MFMA inside)
//
// Block-cooperative, DMA-pipelined version:
//  - 512 threads (8 waves), each wave owns e-slice [wv*16, wv*16+16)
//  - nb tiles (16KB fp32) double-buffered in LDS via global_load_lds,
//    pre-swizzled global source addresses (swizzle-both-sides rule)
//  - counted vmcnt + raw s_barrier: DMA stays in flight across barriers
//  - softmax computed redundantly by all waves -> only 2 barriers per b

#define NNBR 32
#define DIM  128

typedef short  short8 __attribute__((ext_vector_type(8)));
typedef float  f32x4  __attribute__((ext_vector_type(4)));

#define GLL(gsrc, ldst) \
    __builtin_amdgcn_global_load_lds((const __attribute__((address_space(1))) void*)(gsrc), \
                                     (__attribute__((address_space(3))) void*)(ldst), 16, 0, 0)

__device__ __forceinline__ short8 cvt_bf8(float4 a, float4 b) {
    __hip_bfloat162 p0 = __float22bfloat162_rn(make_float2(a.x, a.y));
    __hip_bfloat162 p1 = __float22bfloat162_rn(make_float2(a.z, a.w));
    __hip_bfloat162 p2 = __float22bfloat162_rn(make_float2(b.x, b.y));
    __hip_bfloat162 p3 = __float22bfloat162_rn(make_float2(b.z, b.w));
    union { __hip_bfloat162 h[4]; short8 s; } u;
    u.h[0] = p0; u.h[1] = p1; u.h[2] = p2; u.h[3] = p3;
    return u.s;
}

__global__ __launch_bounds__(512, 4) void hete_agg_kernel(
    const float* __restrict__ selfv,  // [B,128]
    const float* __restrict__ nbr,    // [B,32,128]
    const float* __restrict__ w,      // [128,128]
    const float* __restrict__ q,      // [128,1]
    float* __restrict__ out)          // [B,128]
{
    __shared__ ushort wt[DIM * DIM];          // 32KB: wT[e][k] bf16, XOR-swizzled rows
    __shared__ float  nbuf[2 * NNBR * DIM];   // 32KB: two fp32 nb tiles (swizzled content)
    __shared__ float  scoreP[8 * NNBR];       // 1KB : per-wave score partials

    const int tid = threadIdx.x;
    const int l   = tid & 63;
    const int wv  = tid >> 6;       // wave 0..7 -> e-slice
    const int lr  = l & 15;
    const int lk  = l >> 4;         // 0..3
    const int ecol = wv * 16 + lr;  // this lane's output column

    // ---- stage wT[e][k] (bf16, swizzled) ----
    for (int it = 0; it < 8; ++it) {
        int g  = tid + it * 512;            // float4 index 0..4095
        int d  = g >> 5;                    // k row of w
        int e4 = (g & 31) * 4;              // e col base
        float4 v = *(const float4*)(w + g * 4);
        float xs[4] = {v.x, v.y, v.z, v.w};
        #pragma unroll
        for (int j = 0; j < 4; ++j) {
            int e = e4 + j;
            uint u = __float_as_uint(xs[j]);
            u += 0x7FFFu + ((u >> 16) & 1u);
            wt[e * DIM + (d ^ ((e & 7) << 3))] = (ushort)(u >> 16);
        }
    }
    const float qv  = q[ecol];
    const float q02 = 0.2f * qv;

    __syncthreads();   // one-time; before any DMA is issued

    // ---- block's b range: first 32 blocks take 40, rest 39 (total 20000) ----
    const int bid = blockIdx.x;
    const int b0  = bid * 39 + (bid < 32 ? bid : 32);
    const int cnt = 39 + (bid < 32 ? 1 : 0);

    // ---- per-lane swizzled DMA source offsets (bytes within a tile) ----
    // LDS byte L = (c*8+wv)*1024 + l*16 ; content = nb[row][koff ^ sw]
    int srcoff0, srcoff1;
    {
        int L0 = (wv)*1024 + l*16;
        int r0 = L0 >> 9;
        srcoff0 = r0 * 512 + ((L0 & 511) ^ ((r0 & 7) << 4));
        int L1 = (8 + wv)*1024 + l*16;
        int r1 = L1 >> 9;
        srcoff1 = r1 * 512 + ((L1 & 511) ^ ((r1 & 7) << 4));
    }

    // ---- prologue: self prefetch + 2 tiles in flight ----
    float selfA = selfv[(size_t)b0 * DIM + ecol];
    float selfB = selfv[(size_t)(b0 + 1) * DIM + ecol];
    {
        const char* g0 = (const char*)nbr + (size_t)b0 * 16384;
        const char* g1 = (const char*)nbr + (size_t)(b0 + 1) * 16384;
        char* lb0 = (char*)nbuf + wv * 1024;
        char* lb1 = (char*)nbuf + 16384 + wv * 1024;
        GLL(g0 + srcoff0, lb0);
        GLL(g0 + srcoff1, lb0 + 8192);
        GLL(g1 + srcoff0, lb1);
        GLL(g1 + srcoff1, lb1 + 8192);
    }

    for (int t = 0; t < cnt; ++t) {
        const int cur = t & 1;

        // ---- BAR1: tile t ready (counted vmcnt, never 0) ----
        if (t == 0) { asm volatile("s_waitcnt vmcnt(2)" ::: "memory"); }
        else        { asm volatile("s_waitcnt vmcnt(3)" ::: "memory"); }
        __builtin_amdgcn_s_barrier();
        __builtin_amdgcn_sched_barrier(0);

        // ---- GEMM: acc[mt] = msg rows for this lane's column `ecol` ----
        const char* nb = (const char*)nbuf + cur * 16384;
        f32x4 acc0 = {0.f, 0.f, 0.f, 0.f};
        f32x4 acc1 = {0.f, 0.f, 0.f, 0.f};
        #pragma unroll
        for (int kk = 0; kk < 4; ++kk) {
            const int bcol = (kk * 32 + lk * 8) ^ ((ecol & 7) << 3);
            short8 bf = *(const short8*)(&wt[ecol * DIM + bcol]);
            #pragma unroll
            for (int mt = 0; mt < 2; ++mt) {
                const int row = mt * 16 + lr;
                const int sw  = (row & 7) << 4;
                const int byt = kk * 128 + lk * 32;
                float4 f0 = *(const float4*)(nb + row * 512 + ((byt)      ^ sw));
                float4 f1 = *(const float4*)(nb + row * 512 + ((byt + 16) ^ sw));
                short8 af = cvt_bf8(f0, f1);
                if (mt == 0) acc0 = __builtin_amdgcn_mfma_f32_16x16x32_bf16(af, bf, acc0, 0, 0, 0);
                else         acc1 = __builtin_amdgcn_mfma_f32_16x16x32_bf16(af, bf, acc1, 0, 0, 0);
            }
        }

        // ---- score partials over this wave's 16 e's ----
        // lane holds rows {mt*16 + lk*4 + r}, col ecol
        float sc0[4], sc1[4];
        #pragma unroll
        for (int r = 0; r < 4; ++r) {
            float x0 = selfA * acc0[r];
            sc0[r] = (x0 >= 0.f ? qv : q02) * x0;   // leaky(x)*q
            float x1 = selfA * acc1[r];
            sc1[r] = (x1 >= 0.f ? qv : q02) * x1;
        }
        #pragma unroll
        for (int off = 1; off < 16; off <<= 1) {
            #pragma unroll
            for (int r = 0; r < 4; ++r) {
                sc0[r] += __shfl_xor(sc0[r], off);
                sc1[r] += __shfl_xor(sc1[r], off);
            }
        }
        if (lr == 0) {
            #pragma unroll
            for (int r = 0; r < 4; ++r) {
                scoreP[wv * 32 + lk * 4 + r]      = sc0[r];
                scoreP[wv * 32 + 16 + lk * 4 + r] = sc1[r];
            }
        }

        // ---- BAR2: score partials visible (lgkm only; DMA stays in flight) ----
        asm volatile("s_waitcnt lgkmcnt(0)" ::: "memory");
        __builtin_amdgcn_s_barrier();
        __builtin_amdgcn_sched_barrier(0);

        // ---- prefetch self + tile t+2 (clamped dummy at tail keeps vmcnt uniform) ----
        {
            const int tn = (t + 2 < cnt) ? t + 2 : cnt - 1;
            selfA = selfB;
            selfB = selfv[(size_t)(b0 + tn) * DIM + ecol];
            const char* gn = (const char*)nbr + (size_t)(b0 + tn) * 16384;
            char* lbn = (char*)nbuf + cur * 16384 + wv * 1024;
            GLL(gn + srcoff0, lbn);
            GLL(gn + srcoff1, lbn + 8192);
        }
        __builtin_amdgcn_sched_barrier(0);

        // ---- softmax over 32 neighbors (all waves redundantly; no 3rd barrier) ----
        const int n = l & 31;
        float s = 0.f;
        #pragma unroll
        for (int w8 = 0; w8 < 8; ++w8) s += scoreP[w8 * 32 + n];
        float mx = s;
        #pragma unroll
        for (int off = 1; off < 32; off <<= 1) mx = fmaxf(mx, __shfl_xor(mx, off));
        float ee = __expf(s - mx);
        float sm = ee;
        #pragma unroll
        for (int off = 1; off < 32; off <<= 1) sm += __shfl_xor(sm, off);
        const float al = ee * __builtin_amdgcn_rcpf(sm);   // alpha[n] in lane n (and n+32)

        // ---- weighted sum over neighbors for this lane's column ----
        float o = 0.f;
        #pragma unroll
        for (int r = 0; r < 4; ++r) {
            float a0 = __shfl(al, lk * 4 + r);         // alpha[row], mt=0
            float a1 = __shfl(al, 16 + lk * 4 + r);    // alpha[row], mt=1
            o += a0 * acc0[r] + a1 * acc1[r];
        }
        o += __shfl_xor(o, 16);
        o += __shfl_xor(o, 32);
        if (l < 16) out[(size_t)(b0 + t) * DIM + wv * 16 + l] = o;
    }
}

extern "C" void kernel_launch(void* const* d_in, const int* in_sizes, int n_in,
                              void* d_out, int out_size, void* d_ws, size_t ws_size,
                              hipStream_t stream) {
    const float* selfv = (const float*)d_in[0];
    const float* nbr   = (const float*)d_in[1];
    const float* w     = (const float*)d_in[2];
    const float* q     = (const float*)d_in[3];
    float* out = (float*)d_out;

    // 512 blocks x 512 threads: 2 blocks/CU, blocks own contiguous b-chunks (39/40)
    hete_agg_kernel<<<512, 512, 0, stream>>>(selfv, nbr, w, q, out);
}

// Round 6
// 453.475 us; speedup vs baseline: 1.1170x; 1.1115x over previous
//
#include <hip/hip_runtime.h>
#include <hip/hip_bf16.h>

// HeteAggregator: B=20000, N=32, D=128 (fp32 in/out, bf16 MFMA inside)
//
// 1-wave-per-b, barrier-free version:
//  - each wave owns one b at a time: A (nb) reg-staged global->fp32 regs->bf16,
//    full 32x128 GEMM via 64x mfma_16x16x32, softmax+weighted sum in-wave (shfl)
//  - w: one-time bf16 XOR-swizzled LDS tile (read-only after init -> no barriers)
//  - next-b A+self prefetched into regs mid-compute (deep, ~13K cy slack)
//  - 500 blocks x 256 thr = 2000 waves, 10 b's each, all resident
//
// r4 fix: wt staging loop runs 16 iters (256 thr x 16 x 1 float4 = 4096 = all
// of w); the r3 port kept the 512-thread count (8) and left half of wt
// uninitialized -> NaN.

#define DIM 128

typedef short short8 __attribute__((ext_vector_type(8)));
typedef float f32x4  __attribute__((ext_vector_type(4)));

__device__ __forceinline__ ushort f2bf(float x) {
    uint u = __float_as_uint(x);
    u += 0x7FFFu + ((u >> 16) & 1u);
    return (ushort)(u >> 16);
}

__device__ __forceinline__ short8 cvt_bf8(float4 a, float4 b) {
    __hip_bfloat162 p0 = __float22bfloat162_rn(make_float2(a.x, a.y));
    __hip_bfloat162 p1 = __float22bfloat162_rn(make_float2(a.z, a.w));
    __hip_bfloat162 p2 = __float22bfloat162_rn(make_float2(b.x, b.y));
    __hip_bfloat162 p3 = __float22bfloat162_rn(make_float2(b.z, b.w));
    union { __hip_bfloat162 h[4]; short8 s; } u;
    u.h[0] = p0; u.h[1] = p1; u.h[2] = p2; u.h[3] = p3;
    return u.s;
}

__global__ __launch_bounds__(256, 2) void hete_agg_kernel(
    const float* __restrict__ selfv,  // [B,128]
    const float* __restrict__ nbr,    // [B,32,128]
    const float* __restrict__ w,      // [128,128]
    const float* __restrict__ q,      // [128,1]
    float* __restrict__ out)          // [B,128]
{
    __shared__ ushort wt[DIM * DIM];   // 32KB: wT[e][k] bf16, XOR-swizzled rows

    const int tid = threadIdx.x;

    // ---- one-time: stage wT[e][k] (bf16, 16B-granule XOR swizzle) ----
    #pragma unroll
    for (int it = 0; it < 16; ++it) {
        int g  = tid + it * 256;            // float4 index 0..4095
        int d  = g >> 5;                    // k row of w
        int e4 = (g & 31) * 4;              // e col base
        float4 v = *(const float4*)(w + (size_t)g * 4);
        float xs[4] = {v.x, v.y, v.z, v.w};
        #pragma unroll
        for (int j = 0; j < 4; ++j) {
            int e = e4 + j;
            wt[e * DIM + (d ^ ((e & 7) << 3))] = f2bf(xs[j]);
        }
    }
    __syncthreads();   // the only barrier in the kernel

    const int l   = tid & 63;
    const int wv  = tid >> 6;
    const int lr  = l & 15;     // col within 16x16 tile
    const int lk  = l >> 4;     // k-group / row-group 0..3
    const int wid = blockIdx.x * 4 + wv;    // 0..1999

    float qS[8];
    #pragma unroll
    for (int et = 0; et < 8; ++et) qS[et] = q[et * 16 + lr];

    float4 st[16];              // fp32 A staging (next b)
    float  selfN[8], selfC[8];

    // ---- prologue: prefetch b = wid ----
    {
        const float* nb = nbr + (size_t)wid * (32 * DIM);
        #pragma unroll
        for (int mt = 0; mt < 2; ++mt)
            #pragma unroll
            for (int kk = 0; kk < 4; ++kk)
                #pragma unroll
                for (int c = 0; c < 2; ++c)
                    st[mt * 8 + kk * 2 + c] =
                        *(const float4*)(nb + (mt * 16 + lr) * DIM + kk * 32 + lk * 8 + c * 4);
        #pragma unroll
        for (int et = 0; et < 8; ++et)
            selfN[et] = selfv[(size_t)wid * DIM + et * 16 + lr];
    }

    for (int t = 0; t < 10; ++t) {
        const int b = wid + t * 2000;

        // ---- convert this b's A to bf16 frags (compiler auto-waitcnt) ----
        short8 afrag[2][4];
        #pragma unroll
        for (int mt = 0; mt < 2; ++mt)
            #pragma unroll
            for (int kk = 0; kk < 4; ++kk)
                afrag[mt][kk] = cvt_bf8(st[mt * 8 + kk * 2 + 0], st[mt * 8 + kk * 2 + 1]);
        #pragma unroll
        for (int et = 0; et < 8; ++et) selfC[et] = selfN[et];

        // ---- prefetch next b into freed staging regs ----
        {
            const int bn = (t < 9) ? (b + 2000) : b;   // tail: dummy reload
            const float* nb = nbr + (size_t)bn * (32 * DIM);
            #pragma unroll
            for (int mt = 0; mt < 2; ++mt)
                #pragma unroll
                for (int kk = 0; kk < 4; ++kk)
                    #pragma unroll
                    for (int c = 0; c < 2; ++c)
                        st[mt * 8 + kk * 2 + c] =
                            *(const float4*)(nb + (mt * 16 + lr) * DIM + kk * 32 + lk * 8 + c * 4);
            #pragma unroll
            for (int et = 0; et < 8; ++et)
                selfN[et] = selfv[(size_t)bn * DIM + et * 16 + lr];
        }

        // ---- GEMM: msg = nb x w ; acc[mt][et], D: col=lane&15, row=lk*4+r ----
        f32x4 acc[2][8] = {};
        #pragma unroll
        for (int kk = 0; kk < 4; ++kk) {
            #pragma unroll
            for (int et = 0; et < 8; ++et) {
                const int e = et * 16 + lr;
                short8 bf = *(const short8*)(&wt[e * DIM + ((kk * 32 + lk * 8) ^ ((e & 7) << 3))]);
                acc[0][et] = __builtin_amdgcn_mfma_f32_16x16x32_bf16(afrag[0][kk], bf, acc[0][et], 0, 0, 0);
                acc[1][et] = __builtin_amdgcn_mfma_f32_16x16x32_bf16(afrag[1][kk], bf, acc[1][et], 0, 0, 0);
            }
        }

        // ---- scores: sc[mt][r] = sum_e leaky(self[e]*msg[row][e])*q[e] ----
        float sc[2][4];
        #pragma unroll
        for (int mt = 0; mt < 2; ++mt)
            #pragma unroll
            for (int r = 0; r < 4; ++r) {
                float s = 0.f;
                #pragma unroll
                for (int et = 0; et < 8; ++et) {
                    float x = selfC[et] * acc[mt][et][r];
                    x = (x >= 0.f) ? x : 0.2f * x;      // LeakyReLU
                    s += x * qS[et];
                }
                sc[mt][r] = s;
            }
        #pragma unroll
        for (int off = 1; off < 16; off <<= 1)
            #pragma unroll
            for (int mt = 0; mt < 2; ++mt)
                #pragma unroll
                for (int r = 0; r < 4; ++r)
                    sc[mt][r] += __shfl_xor(sc[mt][r], off);
        // now sc[mt][r] = score[row], row = mt*16 + lk*4 + r (uniform across lr)

        // ---- softmax over 32 rows ----
        float mx = sc[0][0];
        #pragma unroll
        for (int mt = 0; mt < 2; ++mt)
            #pragma unroll
            for (int r = 0; r < 4; ++r) mx = fmaxf(mx, sc[mt][r]);
        mx = fmaxf(mx, __shfl_xor(mx, 16));
        mx = fmaxf(mx, __shfl_xor(mx, 32));
        float p[2][4], S = 0.f;
        #pragma unroll
        for (int mt = 0; mt < 2; ++mt)
            #pragma unroll
            for (int r = 0; r < 4; ++r) { p[mt][r] = __expf(sc[mt][r] - mx); S += p[mt][r]; }
        S += __shfl_xor(S, 16);
        S += __shfl_xor(S, 32);
        const float inv = __builtin_amdgcn_rcpf(S);

        // ---- weighted sum over neighbors: out[e] = sum_row alpha[row]*msg[row][e] ----
        float o[8];
        #pragma unroll
        for (int et = 0; et < 8; ++et) {
            float v = 0.f;
            #pragma unroll
            for (int mt = 0; mt < 2; ++mt)
                #pragma unroll
                for (int r = 0; r < 4; ++r)
                    v += p[mt][r] * acc[mt][et][r];
            o[et] = v * inv;
        }
        #pragma unroll
        for (int et = 0; et < 8; ++et) {
            o[et] += __shfl_xor(o[et], 16);   // sum over lk pairs
            o[et] += __shfl_xor(o[et], 32);
        }

        // ---- store: group lk stores et = {lk*2, lk*2+1} (static indices) ----
        #pragma unroll
        for (int et = 0; et < 8; ++et)
            if (lk == (et >> 1))
                out[(size_t)b * DIM + et * 16 + lr] = o[et];
    }
}

extern "C" void kernel_launch(void* const* d_in, const int* in_sizes, int n_in,
                              void* d_out, int out_size, void* d_ws, size_t ws_size,
                              hipStream_t stream) {
    const float* selfv = (const float*)d_in[0];
    const float* nbr   = (const float*)d_in[1];
    const float* w     = (const float*)d_in[2];
    const float* q     = (const float*)d_in[3];
    float* out = (float*)d_out;

    // 500 blocks x 256 threads = 2000 waves; each wave does exactly 10 b's
    hete_agg_kernel<<<500, 256, 0, stream>>>(selfv, nbr, w, q, out);
}